// Round 5
// baseline (185.351 us; speedup 1.0000x reference)
//
#include <hip/hip_runtime.h>
#include <stdint.h>

#define TABLE_MASK 0x7FFFFu          // TABLE_SIZE = 524288 = 2^19
#define PRIME 2654435761u
#define WORDS_PER_TABLE 65536        // 524288 entries * 4 bits / 32
#define CELLS_PER_PLANE (512 * 512)  // 262144 cells, uint16 each

// ---------------------------------------------------------------------------
// Stage 1: binarize three (524288,4) f32 tables into 4-bit nibbles.
// Entry e -> word e>>3, nibble (e&7); bit f set <=> table[e][f] >= 0 (+1).
// ---------------------------------------------------------------------------
__global__ __launch_bounds__(256) void pack_kernel(
    const float* __restrict__ t0, const float* __restrict__ t1,
    const float* __restrict__ t2, uint32_t* __restrict__ out) {
  uint32_t tid = blockIdx.x * 256u + threadIdx.x;   // 0 .. 3*65536-1
  uint32_t tab = tid >> 16;
  uint32_t word = tid & 65535u;
  const float4* t =
      (const float4*)(tab == 0 ? t0 : (tab == 1 ? t1 : t2)) + word * 8u;
  uint32_t v = 0;
#pragma unroll
  for (int k = 0; k < 8; ++k) {
    float4 f = t[k];
    uint32_t n = (f.x >= 0.0f ? 1u : 0u) | (f.y >= 0.0f ? 2u : 0u) |
                 (f.z >= 0.0f ? 4u : 0u) | (f.w >= 0.0f ? 8u : 0u);
    v |= n << (4 * k);
  }
  out[tid] = v;
}

// ---------------------------------------------------------------------------
// Stage 2: per-cell corner records. For plane p, cell (ia, ib) in [0,512)^2,
// gather the 4 corner nibbles via the hash and pack into one uint16:
// bits [0:3]=n(ia,ib) [4:7]=n(ia,ib+1) [8:11]=n(ia+1,ib) [12:15]=n(ia+1,ib+1)
// ---------------------------------------------------------------------------
__global__ __launch_bounds__(256) void cellify_kernel(
    const uint32_t* __restrict__ pk, uint16_t* __restrict__ cells) {
  uint32_t tid = blockIdx.x * 256u + threadIdx.x;   // 0 .. 3*262144-1
  uint32_t plane = tid >> 18;
  uint32_t ia = (tid >> 9) & 511u;
  uint32_t ib = tid & 511u;
  const uint32_t* t = pk + plane * WORDS_PER_TABLE;
  uint32_t hb0 = ib * PRIME;
  uint32_t hb1 = hb0 + PRIME;                       // (ib+1)*PRIME (wraps ok)
  uint32_t i00 = (ia ^ hb0) & TABLE_MASK;
  uint32_t i01 = (ia ^ hb1) & TABLE_MASK;
  uint32_t i10 = ((ia + 1u) ^ hb0) & TABLE_MASK;
  uint32_t i11 = ((ia + 1u) ^ hb1) & TABLE_MASK;
  uint32_t n00 = (t[i00 >> 3] >> ((i00 & 7u) * 4u)) & 15u;
  uint32_t n01 = (t[i01 >> 3] >> ((i01 & 7u) * 4u)) & 15u;
  uint32_t n10 = (t[i10 >> 3] >> ((i10 & 7u) * 4u)) & 15u;
  uint32_t n11 = (t[i11 >> 3] >> ((i11 & 7u) * 4u)) & 15u;
  cells[tid] = (uint16_t)(n00 | (n01 << 4) | (n10 << 8) | (n11 << 12));
}

// ---------------------------------------------------------------------------
// Stage 3: main kernel — 4 points per thread, 12 gathers issued up-front
// (MLP), vectorized pos loads (3x float4 per thread) and float4 stores.
// p_f = sum of weights whose sign bit is +; out = 2p - 3.
// ---------------------------------------------------------------------------
__device__ __forceinline__ float bitmask_w(float w, uint32_t r, int bit) {
  // w if bit set else 0, branch-free: float & sign-extended bit
  return __uint_as_float(__float_as_uint(w) &
                         (uint32_t)__builtin_amdgcn_sbfe((int)r, bit, 1));
}

__global__ __launch_bounds__(256) void hash_main4(
    const float4* __restrict__ pos4, const uint16_t* __restrict__ cells,
    float4* __restrict__ out4, int nq) {
  int t = (int)(blockIdx.x * 256u + threadIdx.x);
  if (t >= nq) return;
  float4 A = pos4[3 * t + 0];
  float4 B = pos4[3 * t + 1];
  float4 C = pos4[3 * t + 2];
  float X[4] = {A.x, A.w, B.z, C.y};
  float Y[4] = {A.y, B.x, B.w, C.z};
  float Z[4] = {A.z, B.y, C.x, C.w};

  float WA[12], WB[12];
  uint32_t R[12];
  // Phase 1: compute all 12 addresses, issue all 12 gathers (independent).
#pragma unroll
  for (int k = 0; k < 4; ++k) {
    float pa[3] = {X[k], X[k], Y[k]};
    float pb[3] = {Y[k], Z[k], Z[k]};
#pragma unroll
    for (int p = 0; p < 3; ++p) {
      float sa = pa[p] * 512.0f, sb = pb[p] * 512.0f;
      float fa = floorf(sa), fb = floorf(sb);
      WA[3 * k + p] = sa - fa;
      WB[3 * k + p] = sb - fb;
      uint32_t ia = (uint32_t)fa, ib = (uint32_t)fb;
      R[3 * k + p] = cells[p * CELLS_PER_PLANE + ((ia << 9) | ib)];
    }
  }
  // Phase 2: consume.
#pragma unroll
  for (int k = 0; k < 4; ++k) {
    float q0 = 0.f, q1 = 0.f, q2 = 0.f, q3 = 0.f;
#pragma unroll
    for (int p = 0; p < 3; ++p) {
      uint32_t r = R[3 * k + p];
      float wa = WA[3 * k + p], wb = WB[3 * k + p];
      float omwa = 1.0f - wa, omwb = 1.0f - wb;
      float v00 = omwa * omwb, v01 = omwa * wb, v10 = wa * omwb, v11 = wa * wb;
      q0 += bitmask_w(v00, r, 0) + bitmask_w(v01, r, 4) +
            bitmask_w(v10, r, 8) + bitmask_w(v11, r, 12);
      q1 += bitmask_w(v00, r, 1) + bitmask_w(v01, r, 5) +
            bitmask_w(v10, r, 9) + bitmask_w(v11, r, 13);
      q2 += bitmask_w(v00, r, 2) + bitmask_w(v01, r, 6) +
            bitmask_w(v10, r, 10) + bitmask_w(v11, r, 14);
      q3 += bitmask_w(v00, r, 3) + bitmask_w(v01, r, 7) +
            bitmask_w(v10, r, 11) + bitmask_w(v11, r, 15);
    }
    float4 o;
    o.x = fmaf(2.0f, q0, -3.0f);   // sum over 3 planes of (2*q_plane - 1)
    o.y = fmaf(2.0f, q1, -3.0f);
    o.z = fmaf(2.0f, q2, -3.0f);
    o.w = fmaf(2.0f, q3, -3.0f);
    out4[4 * t + k] = o;
  }
}

// Scalar tail kernel (n % 4 != 0) — also the generic single-point path.
__device__ __forceinline__ void plane_cell(
    const uint16_t* __restrict__ cells, float a, float b,
    float& p0, float& p1, float& p2, float& p3) {
  float sa = a * 512.0f, sb = b * 512.0f;
  float fa = floorf(sa), fb = floorf(sb);
  float wa = sa - fa, wb = sb - fb;
  uint32_t ia = (uint32_t)fa, ib = (uint32_t)fb;
  uint32_t r = cells[(ia << 9) | ib];
  float omwa = 1.0f - wa, omwb = 1.0f - wb;
  float v00 = omwa * omwb, v01 = omwa * wb, v10 = wa * omwb, v11 = wa * wb;
  p0 += bitmask_w(v00, r, 0) + bitmask_w(v01, r, 4) + bitmask_w(v10, r, 8) +
        bitmask_w(v11, r, 12);
  p1 += bitmask_w(v00, r, 1) + bitmask_w(v01, r, 5) + bitmask_w(v10, r, 9) +
        bitmask_w(v11, r, 13);
  p2 += bitmask_w(v00, r, 2) + bitmask_w(v01, r, 6) + bitmask_w(v10, r, 10) +
        bitmask_w(v11, r, 14);
  p3 += bitmask_w(v00, r, 3) + bitmask_w(v01, r, 7) + bitmask_w(v10, r, 11) +
        bitmask_w(v11, r, 15);
}

__global__ __launch_bounds__(256) void hash_tail(
    const float* __restrict__ pos, const uint16_t* __restrict__ cells,
    float4* __restrict__ out, int n, int start) {
  int i = start + (int)(blockIdx.x * 256u + threadIdx.x);
  if (i >= n) return;
  float x = pos[3 * i + 0];
  float y = pos[3 * i + 1];
  float z = pos[3 * i + 2];
  float p0 = 0.f, p1 = 0.f, p2 = 0.f, p3 = 0.f;
  plane_cell(cells, x, y, p0, p1, p2, p3);
  plane_cell(cells + CELLS_PER_PLANE, x, z, p0, p1, p2, p3);
  plane_cell(cells + 2 * CELLS_PER_PLANE, y, z, p0, p1, p2, p3);
  float4 o;
  o.x = fmaf(2.0f, p0, -3.0f);
  o.y = fmaf(2.0f, p1, -3.0f);
  o.z = fmaf(2.0f, p2, -3.0f);
  o.w = fmaf(2.0f, p3, -3.0f);
  out[i] = o;
}

// ---------------------------------------------------------------------------
// Fallback (ws fits pack only): gather packed nibbles directly via hash.
// ---------------------------------------------------------------------------
__device__ __forceinline__ void plane_accum(
    const uint32_t* __restrict__ t, float a, float b,
    float& p0, float& p1, float& p2, float& p3) {
  float sa = a * 512.0f, sb = b * 512.0f;
  float fa = floorf(sa), fb = floorf(sb);
  float wa = sa - fa, wb = sb - fb;
  uint32_t ia = (uint32_t)fa, ib = (uint32_t)fb;
  uint32_t hb0 = ib * PRIME;
  uint32_t hb1 = hb0 + PRIME;
  uint32_t i00 = (ia ^ hb0) & TABLE_MASK;
  uint32_t i01 = (ia ^ hb1) & TABLE_MASK;
  uint32_t d = ia ^ (ia + 1u);
  uint32_t i10 = i00 ^ d;
  uint32_t i11 = i01 ^ d;
  uint32_t w00 = t[i00 >> 3];
  uint32_t w01 = t[i01 >> 3];
  uint32_t w10 = w00, w11 = w01;
  if (d >= 8u) {
    w10 = t[i10 >> 3];
    w11 = t[i11 >> 3];
  }
  uint32_t n00 = w00 >> ((i00 & 7u) * 4u);
  uint32_t n01 = w01 >> ((i01 & 7u) * 4u);
  uint32_t n10 = w10 >> ((i10 & 7u) * 4u);
  uint32_t n11 = w11 >> ((i11 & 7u) * 4u);
  float omwa = 1.0f - wa, omwb = 1.0f - wb;
  float v00 = omwa * omwb, v01 = omwa * wb, v10 = wa * omwb, v11 = wa * wb;
  p0 += bitmask_w(v00, n00, 0) + bitmask_w(v01, n01, 0) +
        bitmask_w(v10, n10, 0) + bitmask_w(v11, n11, 0);
  p1 += bitmask_w(v00, n00, 1) + bitmask_w(v01, n01, 1) +
        bitmask_w(v10, n10, 1) + bitmask_w(v11, n11, 1);
  p2 += bitmask_w(v00, n00, 2) + bitmask_w(v01, n01, 2) +
        bitmask_w(v10, n10, 2) + bitmask_w(v11, n11, 2);
  p3 += bitmask_w(v00, n00, 3) + bitmask_w(v01, n01, 3) +
        bitmask_w(v10, n10, 3) + bitmask_w(v11, n11, 3);
}

__global__ __launch_bounds__(256) void hash_packed(
    const float* __restrict__ pos, const uint32_t* __restrict__ pk,
    float4* __restrict__ out, int n) {
  int i = (int)(blockIdx.x * 256u + threadIdx.x);
  if (i >= n) return;
  float x = pos[3 * i + 0];
  float y = pos[3 * i + 1];
  float z = pos[3 * i + 2];
  float p0 = 0.f, p1 = 0.f, p2 = 0.f, p3 = 0.f;
  plane_accum(pk, x, y, p0, p1, p2, p3);
  plane_accum(pk + WORDS_PER_TABLE, x, z, p0, p1, p2, p3);
  plane_accum(pk + 2 * WORDS_PER_TABLE, y, z, p0, p1, p2, p3);
  float4 o;
  o.x = fmaf(2.0f, p0, -3.0f);
  o.y = fmaf(2.0f, p1, -3.0f);
  o.z = fmaf(2.0f, p2, -3.0f);
  o.w = fmaf(2.0f, p3, -3.0f);
  out[i] = o;
}

extern "C" void kernel_launch(void* const* d_in, const int* in_sizes, int n_in,
                              void* d_out, int out_size, void* d_ws,
                              size_t ws_size, hipStream_t stream) {
  const float* pos = (const float*)d_in[0];
  const float* txy = (const float*)d_in[1];
  const float* txz = (const float*)d_in[2];
  const float* tyz = (const float*)d_in[3];
  float4* out = (float4*)d_out;
  int n = in_sizes[0] / 3;                       // 4194304
  const size_t pk_bytes = (size_t)3 * WORDS_PER_TABLE * 4;        // 768 KB
  const size_t cell_bytes = (size_t)3 * CELLS_PER_PLANE * 2;      // 1.5 MB
  if (ws_size >= pk_bytes + cell_bytes) {
    uint32_t* pk = (uint32_t*)d_ws;
    uint16_t* cells = (uint16_t*)((char*)d_ws + pk_bytes);
    pack_kernel<<<3 * WORDS_PER_TABLE / 256, 256, 0, stream>>>(txy, txz, tyz,
                                                               pk);
    cellify_kernel<<<3 * CELLS_PER_PLANE / 256, 256, 0, stream>>>(pk, cells);
    int nq = n / 4;
    if (nq > 0)
      hash_main4<<<(nq + 255) / 256, 256, 0, stream>>>(
          (const float4*)pos, cells, out, nq);
    int rem = n - nq * 4;
    if (rem > 0)
      hash_tail<<<(rem + 255) / 256, 256, 0, stream>>>(pos, cells, out, n,
                                                       nq * 4);
  } else {
    uint32_t* pk = (uint32_t*)d_ws;
    pack_kernel<<<3 * WORDS_PER_TABLE / 256, 256, 0, stream>>>(txy, txz, tyz,
                                                               pk);
    hash_packed<<<(n + 255) / 256, 256, 0, stream>>>(pos, pk, out, n);
  }
}

// Round 7
// 183.387 us; speedup vs baseline: 1.0107x; 1.0107x over previous
//
#include <hip/hip_runtime.h>
#include <stdint.h>

#define TABLE_MASK 0x7FFFFu          // TABLE_SIZE = 524288 = 2^19
#define PRIME 2654435761u
#define WORDS_PER_TABLE 65536        // 524288 entries * 4 bits / 32
#define CELLS_PER_PLANE (512 * 512)  // 262144 cells, uint16 each
#define CORNER_DWORDS 32961          // 513 rows * 514 nibbles / 8 = 131844 B /4
#define CORNER_BYTES (CORNER_DWORDS * 4)

// ---------------------------------------------------------------------------
// Stage 1: binarize three (524288,4) f32 tables into 4-bit nibbles.
// Entry e -> word e>>3, nibble (e&7); bit f set <=> table[e][f] >= 0 (+1).
// ---------------------------------------------------------------------------
__global__ __launch_bounds__(256) void pack_kernel(
    const float* __restrict__ t0, const float* __restrict__ t1,
    const float* __restrict__ t2, uint32_t* __restrict__ out) {
  uint32_t tid = blockIdx.x * 256u + threadIdx.x;   // 0 .. 3*65536-1
  uint32_t tab = tid >> 16;
  uint32_t word = tid & 65535u;
  const float4* t =
      (const float4*)(tab == 0 ? t0 : (tab == 1 ? t1 : t2)) + word * 8u;
  uint32_t v = 0;
#pragma unroll
  for (int k = 0; k < 8; ++k) {
    float4 f = t[k];
    uint32_t n = (f.x >= 0.0f ? 1u : 0u) | (f.y >= 0.0f ? 2u : 0u) |
                 (f.z >= 0.0f ? 4u : 0u) | (f.w >= 0.0f ? 8u : 0u);
    v |= n << (4 * k);
  }
  out[tid] = v;
}

// ---------------------------------------------------------------------------
// Stage 2a: cell records for the xz (p'=0) and yz (p'=1) planes only.
// bits [0:3]=n(ia,ib) [4:7]=n(ia,ib+1) [8:11]=n(ia+1,ib) [12:15]=n(ia+1,ib+1)
// ---------------------------------------------------------------------------
__global__ __launch_bounds__(256) void cellify2_kernel(
    const uint32_t* __restrict__ pk, uint16_t* __restrict__ cells2) {
  uint32_t tid = blockIdx.x * 256u + threadIdx.x;   // 0 .. 2*262144-1
  uint32_t pp = tid >> 18;                          // 0=xz, 1=yz
  uint32_t ia = (tid >> 9) & 511u;
  uint32_t ib = tid & 511u;
  const uint32_t* t = pk + (pp + 1) * WORDS_PER_TABLE;
  uint32_t hb0 = ib * PRIME;
  uint32_t hb1 = hb0 + PRIME;
  uint32_t i00 = (ia ^ hb0) & TABLE_MASK;
  uint32_t i01 = (ia ^ hb1) & TABLE_MASK;
  uint32_t d = ia ^ (ia + 1u);                      // +x corners share word 7/8
  uint32_t i10 = i00 ^ d;
  uint32_t i11 = i01 ^ d;
  uint32_t w00 = t[i00 >> 3];
  uint32_t w01 = t[i01 >> 3];
  uint32_t w10 = w00, w11 = w01;
  if (d >= 8u) {
    w10 = t[i10 >> 3];
    w11 = t[i11 >> 3];
  }
  uint32_t n00 = (w00 >> ((i00 & 7u) * 4u)) & 15u;
  uint32_t n01 = (w01 >> ((i01 & 7u) * 4u)) & 15u;
  uint32_t n10 = (w10 >> ((i10 & 7u) * 4u)) & 15u;
  uint32_t n11 = (w11 >> ((i11 & 7u) * 4u)) & 15u;
  cells2[tid] = (uint16_t)(n00 | (n01 << 4) | (n10 << 8) | (n11 << 12));
}

// ---------------------------------------------------------------------------
// Stage 2b: dense corner-nibble table for the xy plane.
// Corner (ix,iy), ix,iy in [0,512]: nibble index ci = ix*514 + iy.
// Thread t fills dword t (nibbles 8t..8t+7). Out-of-range -> 0.
// ---------------------------------------------------------------------------
__global__ __launch_bounds__(256) void corner_kernel(
    const uint32_t* __restrict__ pk, uint32_t* __restrict__ cornerg) {
  uint32_t t = blockIdx.x * 256u + threadIdx.x;
  if (t >= CORNER_DWORDS) return;
  uint32_t d = 0;
#pragma unroll
  for (int k = 0; k < 8; ++k) {
    uint32_t ci = 8u * t + (uint32_t)k;
    uint32_t ix = ci / 514u;
    uint32_t iy = ci - 514u * ix;
    uint32_t nib = 0;
    if (iy <= 512u) {                                // ix <= 512 by size
      uint32_t idx = (ix ^ (iy * PRIME)) & TABLE_MASK;
      nib = (pk[idx >> 3] >> ((idx & 7u) * 4u)) & 15u;
    }
    d |= nib << (4 * k);
  }
  cornerg[t] = d;
}

// ---------------------------------------------------------------------------
// Stage 3: main kernel. xy plane answered from an LDS-resident corner table
// (4x ds_read_u8, no TCP misses); xz/yz from L2-resident cell tables
// (2 gathers/point, issued 8-deep before consumption).
// p_f = sum of weights whose sign bit is +; out = 2p - 3.
// ---------------------------------------------------------------------------
__device__ __forceinline__ float bitmask_w(float w, uint32_t r, int bit) {
  return __uint_as_float(__float_as_uint(w) &
                         (uint32_t)__builtin_amdgcn_sbfe((int)r, bit, 1));
}

__device__ __forceinline__ void acc_rec(uint32_t r, float wa, float wb,
                                        float& q0, float& q1, float& q2,
                                        float& q3) {
  float omwa = 1.0f - wa, omwb = 1.0f - wb;
  float v00 = omwa * omwb, v01 = omwa * wb, v10 = wa * omwb, v11 = wa * wb;
  q0 += bitmask_w(v00, r, 0) + bitmask_w(v01, r, 4) + bitmask_w(v10, r, 8) +
        bitmask_w(v11, r, 12);
  q1 += bitmask_w(v00, r, 1) + bitmask_w(v01, r, 5) + bitmask_w(v10, r, 9) +
        bitmask_w(v11, r, 13);
  q2 += bitmask_w(v00, r, 2) + bitmask_w(v01, r, 6) + bitmask_w(v10, r, 10) +
        bitmask_w(v11, r, 14);
  q3 += bitmask_w(v00, r, 3) + bitmask_w(v01, r, 7) + bitmask_w(v10, r, 11) +
        bitmask_w(v11, r, 15);
}

__global__ __launch_bounds__(1024, 1) void hash_lds(
    const float4* __restrict__ pos4, const uint16_t* __restrict__ cells2,
    const uint32_t* __restrict__ cornerg, float4* __restrict__ out4, int nq) {
  extern __shared__ uint32_t lds4[];
  for (int j = (int)threadIdx.x; j < CORNER_DWORDS; j += 1024)
    lds4[j] = cornerg[j];
  __syncthreads();
  int t = (int)(blockIdx.x * 1024u + threadIdx.x);
  if (t >= nq) return;
  float4 A = pos4[3 * t + 0];
  float4 B = pos4[3 * t + 1];
  float4 C = pos4[3 * t + 2];
  float X[4] = {A.x, A.w, B.z, C.y};
  float Y[4] = {A.y, B.x, B.w, C.z};
  float Z[4] = {A.z, B.y, C.x, C.w};

  // Phase 1: issue all 8 global gathers (xz, yz per point).
  float WAxz[4], WByz[4], WAyz[4], WZ[4];
  uint32_t Gxz[4], Gyz[4];
#pragma unroll
  for (int k = 0; k < 4; ++k) {
    float sx = X[k] * 512.0f, sy = Y[k] * 512.0f, sz = Z[k] * 512.0f;
    float fx = floorf(sx), fy = floorf(sy), fz = floorf(sz);
    uint32_t ix = (uint32_t)fx, iy = (uint32_t)fy, iz = (uint32_t)fz;
    WAxz[k] = sx - fx;
    WAyz[k] = sy - fy;
    WZ[k] = sz - fz;
    WByz[k] = WZ[k];
    Gxz[k] = cells2[(ix << 9) | iz];
    Gyz[k] = cells2[CELLS_PER_PLANE + ((iy << 9) | iz)];
  }
  __builtin_amdgcn_sched_barrier(0);

  // Phase 2: xy from LDS + consume gathers.
  const uint8_t* lb = (const uint8_t*)lds4;
#pragma unroll
  for (int k = 0; k < 4; ++k) {
    float sa = X[k] * 512.0f, sb = Y[k] * 512.0f;
    float fa = floorf(sa), fb = floorf(sb);
    float wa = sa - fa, wb = sb - fb;
    uint32_t ia = (uint32_t)fa, ib = (uint32_t)fb;
    uint32_t r0 = ia * 257u, r1 = r0 + 257u;
    uint32_t c0 = ib >> 1, c1 = (ib + 1u) >> 1;
    uint32_t s0 = (ib & 1u) * 4u, s1 = ((ib + 1u) & 1u) * 4u;
    uint32_t n00 = ((uint32_t)lb[r0 + c0] >> s0) & 15u;
    uint32_t n01 = ((uint32_t)lb[r0 + c1] >> s1) & 15u;
    uint32_t n10 = ((uint32_t)lb[r1 + c0] >> s0) & 15u;
    uint32_t n11 = ((uint32_t)lb[r1 + c1] >> s1) & 15u;
    uint32_t rxy = n00 | (n01 << 4) | (n10 << 8) | (n11 << 12);
    float q0 = 0.f, q1 = 0.f, q2 = 0.f, q3 = 0.f;
    acc_rec(rxy, wa, wb, q0, q1, q2, q3);
    acc_rec(Gxz[k], WAxz[k], WZ[k], q0, q1, q2, q3);
    acc_rec(Gyz[k], WAyz[k], WByz[k], q0, q1, q2, q3);
    float4 o;
    o.x = fmaf(2.0f, q0, -3.0f);
    o.y = fmaf(2.0f, q1, -3.0f);
    o.z = fmaf(2.0f, q2, -3.0f);
    o.w = fmaf(2.0f, q3, -3.0f);
    out4[4 * t + k] = o;
  }
}

// ---------------------------------------------------------------------------
// Fallback pipeline (round-3): 3-plane cell table, 4 pts/thread, no LDS.
// ---------------------------------------------------------------------------
__global__ __launch_bounds__(256) void cellify_kernel(
    const uint32_t* __restrict__ pk, uint16_t* __restrict__ cells) {
  uint32_t tid = blockIdx.x * 256u + threadIdx.x;   // 0 .. 3*262144-1
  uint32_t plane = tid >> 18;
  uint32_t ia = (tid >> 9) & 511u;
  uint32_t ib = tid & 511u;
  const uint32_t* t = pk + plane * WORDS_PER_TABLE;
  uint32_t hb0 = ib * PRIME;
  uint32_t hb1 = hb0 + PRIME;
  uint32_t i00 = (ia ^ hb0) & TABLE_MASK;
  uint32_t i01 = (ia ^ hb1) & TABLE_MASK;
  uint32_t i10 = ((ia + 1u) ^ hb0) & TABLE_MASK;
  uint32_t i11 = ((ia + 1u) ^ hb1) & TABLE_MASK;
  uint32_t n00 = (t[i00 >> 3] >> ((i00 & 7u) * 4u)) & 15u;
  uint32_t n01 = (t[i01 >> 3] >> ((i01 & 7u) * 4u)) & 15u;
  uint32_t n10 = (t[i10 >> 3] >> ((i10 & 7u) * 4u)) & 15u;
  uint32_t n11 = (t[i11 >> 3] >> ((i11 & 7u) * 4u)) & 15u;
  cells[tid] = (uint16_t)(n00 | (n01 << 4) | (n10 << 8) | (n11 << 12));
}

__global__ __launch_bounds__(256) void hash_main4(
    const float4* __restrict__ pos4, const uint16_t* __restrict__ cells,
    float4* __restrict__ out4, int nq) {
  int t = (int)(blockIdx.x * 256u + threadIdx.x);
  if (t >= nq) return;
  float4 A = pos4[3 * t + 0];
  float4 B = pos4[3 * t + 1];
  float4 C = pos4[3 * t + 2];
  float X[4] = {A.x, A.w, B.z, C.y};
  float Y[4] = {A.y, B.x, B.w, C.z};
  float Z[4] = {A.z, B.y, C.x, C.w};
  float WA[12], WB[12];
  uint32_t R[12];
#pragma unroll
  for (int k = 0; k < 4; ++k) {
    float pa[3] = {X[k], X[k], Y[k]};
    float pb[3] = {Y[k], Z[k], Z[k]};
#pragma unroll
    for (int p = 0; p < 3; ++p) {
      float sa = pa[p] * 512.0f, sb = pb[p] * 512.0f;
      float fa = floorf(sa), fb = floorf(sb);
      WA[3 * k + p] = sa - fa;
      WB[3 * k + p] = sb - fb;
      uint32_t ia = (uint32_t)fa, ib = (uint32_t)fb;
      R[3 * k + p] = cells[p * CELLS_PER_PLANE + ((ia << 9) | ib)];
    }
  }
#pragma unroll
  for (int k = 0; k < 4; ++k) {
    float q0 = 0.f, q1 = 0.f, q2 = 0.f, q3 = 0.f;
#pragma unroll
    for (int p = 0; p < 3; ++p)
      acc_rec(R[3 * k + p], WA[3 * k + p], WB[3 * k + p], q0, q1, q2, q3);
    float4 o;
    o.x = fmaf(2.0f, q0, -3.0f);
    o.y = fmaf(2.0f, q1, -3.0f);
    o.z = fmaf(2.0f, q2, -3.0f);
    o.w = fmaf(2.0f, q3, -3.0f);
    out4[4 * t + k] = o;
  }
}

__global__ __launch_bounds__(256) void hash_tail(
    const float* __restrict__ pos, const uint16_t* __restrict__ cells,
    float4* __restrict__ out, int n, int start) {
  int i = start + (int)(blockIdx.x * 256u + threadIdx.x);
  if (i >= n) return;
  float x = pos[3 * i + 0];
  float y = pos[3 * i + 1];
  float z = pos[3 * i + 2];
  float q0 = 0.f, q1 = 0.f, q2 = 0.f, q3 = 0.f;
  {
    float sa = x * 512.0f, sb = y * 512.0f;
    float fa = floorf(sa), fb = floorf(sb);
    uint32_t ia = (uint32_t)fa, ib = (uint32_t)fb;
    acc_rec(cells[(ia << 9) | ib], sa - fa, sb - fb, q0, q1, q2, q3);
  }
  {
    float sa = x * 512.0f, sb = z * 512.0f;
    float fa = floorf(sa), fb = floorf(sb);
    uint32_t ia = (uint32_t)fa, ib = (uint32_t)fb;
    acc_rec(cells[CELLS_PER_PLANE + ((ia << 9) | ib)], sa - fa, sb - fb, q0,
            q1, q2, q3);
  }
  {
    float sa = y * 512.0f, sb = z * 512.0f;
    float fa = floorf(sa), fb = floorf(sb);
    uint32_t ia = (uint32_t)fa, ib = (uint32_t)fb;
    acc_rec(cells[2 * CELLS_PER_PLANE + ((ia << 9) | ib)], sa - fa, sb - fb,
            q0, q1, q2, q3);
  }
  float4 o;
  o.x = fmaf(2.0f, q0, -3.0f);
  o.y = fmaf(2.0f, q1, -3.0f);
  o.z = fmaf(2.0f, q2, -3.0f);
  o.w = fmaf(2.0f, q3, -3.0f);
  out[i] = o;
}

extern "C" void kernel_launch(void* const* d_in, const int* in_sizes, int n_in,
                              void* d_out, int out_size, void* d_ws,
                              size_t ws_size, hipStream_t stream) {
  const float* pos = (const float*)d_in[0];
  const float* txy = (const float*)d_in[1];
  const float* txz = (const float*)d_in[2];
  const float* tyz = (const float*)d_in[3];
  float4* out = (float4*)d_out;
  int n = in_sizes[0] / 3;                       // 4194304
  const size_t pk_bytes = (size_t)3 * WORDS_PER_TABLE * 4;        // 768 KB
  const size_t cell2_bytes = (size_t)2 * CELLS_PER_PLANE * 2;     // 1.0 MB
  const size_t cell3_bytes = (size_t)3 * CELLS_PER_PLANE * 2;     // 1.5 MB
  const size_t lds_bytes = (size_t)CORNER_BYTES;                  // 131844

  bool lds_ok = (n % 4096 == 0) &&
                ws_size >= pk_bytes + cell2_bytes + CORNER_BYTES;
  if (lds_ok) {
    hipError_t e = hipFuncSetAttribute(
        (const void*)hash_lds, hipFuncAttributeMaxDynamicSharedMemorySize,
        (int)lds_bytes);
    if (e != hipSuccess) lds_ok = false;
  }

  if (lds_ok) {
    uint32_t* pk = (uint32_t*)d_ws;
    uint16_t* cells2 = (uint16_t*)((char*)d_ws + pk_bytes);
    uint32_t* cornerg = (uint32_t*)((char*)d_ws + pk_bytes + cell2_bytes);
    pack_kernel<<<3 * WORDS_PER_TABLE / 256, 256, 0, stream>>>(txy, txz, tyz,
                                                               pk);
    cellify2_kernel<<<2 * CELLS_PER_PLANE / 256, 256, 0, stream>>>(pk, cells2);
    corner_kernel<<<(CORNER_DWORDS + 255) / 256, 256, 0, stream>>>(pk,
                                                                   cornerg);
    int nq = n / 4;
    hash_lds<<<(nq + 1023) / 1024, 1024, lds_bytes, stream>>>(
        (const float4*)pos, cells2, cornerg, out, nq);
  } else if (ws_size >= pk_bytes + cell3_bytes) {
    uint32_t* pk = (uint32_t*)d_ws;
    uint16_t* cells = (uint16_t*)((char*)d_ws + pk_bytes);
    pack_kernel<<<3 * WORDS_PER_TABLE / 256, 256, 0, stream>>>(txy, txz, tyz,
                                                               pk);
    cellify_kernel<<<3 * CELLS_PER_PLANE / 256, 256, 0, stream>>>(pk, cells);
    int nq = n / 4;
    if (nq > 0)
      hash_main4<<<(nq + 255) / 256, 256, 0, stream>>>((const float4*)pos,
                                                       cells, out, nq);
    int rem = n - nq * 4;
    if (rem > 0)
      hash_tail<<<(rem + 255) / 256, 256, 0, stream>>>(pos, cells, out, n,
                                                       nq * 4);
  }
}

// Round 9
// 165.669 us; speedup vs baseline: 1.1188x; 1.1069x over previous
//
#include <hip/hip_runtime.h>
#include <stdint.h>

#define TABLE_MASK 0x7FFFFu          // TABLE_SIZE = 524288 = 2^19
#define PRIME 2654435761u
#define CORNER_DWORDS 32961          // 513 rows * 514 nibbles / 8 -> 131844 B
#define CORNER_BYTES (CORNER_DWORDS * 4)
#define PTS_PER_BLOCK 16384          // 1024 threads * 16 points

// ---------------------------------------------------------------------------
// Setup: dense corner-nibble tables for all 3 planes, directly from f32
// tables. Corner (ia,ib), both in [0,512]: nibble ci = ia*514 + ib.
// bit f set <=> table[hash(ia,ib)][f] >= 0 (+1 under sign-STE binarize).
// ---------------------------------------------------------------------------
__global__ __launch_bounds__(256) void corner3_kernel(
    const float* __restrict__ t0, const float* __restrict__ t1,
    const float* __restrict__ t2, uint32_t* __restrict__ cornerg) {
  uint32_t t = blockIdx.x * 256u + threadIdx.x;     // 0 .. 3*CORNER_DWORDS-1
  if (t >= 3u * CORNER_DWORDS) return;
  uint32_t plane = t / CORNER_DWORDS;
  uint32_t w = t - plane * CORNER_DWORDS;
  const float4* tab =
      (const float4*)(plane == 0 ? t0 : (plane == 1 ? t1 : t2));
  uint32_t d = 0;
#pragma unroll
  for (int k = 0; k < 8; ++k) {
    uint32_t ci = 8u * w + (uint32_t)k;
    uint32_t ia = ci / 514u;
    uint32_t ib = ci - 514u * ia;
    uint32_t nib = 0;
    if (ia <= 512u && ib <= 512u) {
      uint32_t idx = (ia ^ (ib * PRIME)) & TABLE_MASK;
      float4 f = tab[idx];
      nib = (f.x >= 0.0f ? 1u : 0u) | (f.y >= 0.0f ? 2u : 0u) |
            (f.z >= 0.0f ? 4u : 0u) | (f.w >= 0.0f ? 8u : 0u);
    }
    d |= nib << (4 * k);
  }
  cornerg[t] = d;
}

// ---------------------------------------------------------------------------
// Main: 3-phase LDS kernel, zero divergent global gathers.
// Block owns 16384 points; acc[16][4] lives in VGPRs across phases.
// Phase p loads plane p's 132 KB corner table into LDS, then all corner
// lookups are ds_read_u8. p_f = sum of weights whose bit is set (in [0,1]);
// out = 2*(p_xy+p_xz+p_yz) - 3.
// ---------------------------------------------------------------------------
__device__ __forceinline__ float bitmask_w(float w, uint32_t r, int bit) {
  // w if bit set else 0, branch-free: float & sign-extended bit
  return __uint_as_float(__float_as_uint(w) &
                         (uint32_t)__builtin_amdgcn_sbfe((int)r, bit, 1));
}

__global__ __launch_bounds__(1024, 4) void hash_planes(
    const float* __restrict__ pos, const uint32_t* __restrict__ cornerg,
    float4* __restrict__ out4, int n) {
  extern __shared__ uint32_t lds4[];
  const uint8_t* lb = (const uint8_t*)lds4;
  int base = (int)(blockIdx.x * (uint32_t)PTS_PER_BLOCK);

  float acc[16][4];
#pragma unroll
  for (int j = 0; j < 16; ++j) {
    acc[j][0] = 0.f;
    acc[j][1] = 0.f;
    acc[j][2] = 0.f;
    acc[j][3] = 0.f;
  }

  for (int ph = 0; ph < 3; ++ph) {
    __syncthreads();  // previous phase's LDS consumers done before overwrite
    const uint32_t* src = cornerg + ph * CORNER_DWORDS;
    for (int j = (int)threadIdx.x; j < CORNER_DWORDS; j += 1024)
      lds4[j] = src[j];
    __syncthreads();

    // coord selector: ph0 -> (x,y), ph1 -> (x,z), ph2 -> (y,z)
    int ca = (ph == 2) ? 1 : 0;
    int cb = (ph == 0) ? 1 : 2;

#pragma unroll
    for (int j = 0; j < 16; ++j) {
      int pt = base + j * 1024 + (int)threadIdx.x;
      if (pt < n) {
        float a = pos[3 * pt + ca];
        float b = pos[3 * pt + cb];
        float sa = a * 512.0f, sb = b * 512.0f;
        float fa = floorf(sa), fb = floorf(sb);
        float wa = sa - fa, wb = sb - fb;
        uint32_t ia = (uint32_t)fa, ib = (uint32_t)fb;
        // byte index = (ia*514 + ib)/2 = ia*257 + ib/2 (514 even)
        uint32_t r0 = ia * 257u, r1 = r0 + 257u;
        uint32_t c0 = ib >> 1, c1 = (ib + 1u) >> 1;
        uint32_t s0 = (ib & 1u) * 4u, s1 = ((ib + 1u) & 1u) * 4u;
        uint32_t n00 = ((uint32_t)lb[r0 + c0] >> s0) & 15u;
        uint32_t n01 = ((uint32_t)lb[r0 + c1] >> s1) & 15u;
        uint32_t n10 = ((uint32_t)lb[r1 + c0] >> s0) & 15u;
        uint32_t n11 = ((uint32_t)lb[r1 + c1] >> s1) & 15u;
        uint32_t r = n00 | (n01 << 4) | (n10 << 8) | (n11 << 12);
        float omwa = 1.0f - wa, omwb = 1.0f - wb;
        float v00 = omwa * omwb, v01 = omwa * wb;
        float v10 = wa * omwb, v11 = wa * wb;
        acc[j][0] += bitmask_w(v00, r, 0) + bitmask_w(v01, r, 4) +
                     bitmask_w(v10, r, 8) + bitmask_w(v11, r, 12);
        acc[j][1] += bitmask_w(v00, r, 1) + bitmask_w(v01, r, 5) +
                     bitmask_w(v10, r, 9) + bitmask_w(v11, r, 13);
        acc[j][2] += bitmask_w(v00, r, 2) + bitmask_w(v01, r, 6) +
                     bitmask_w(v10, r, 10) + bitmask_w(v11, r, 14);
        acc[j][3] += bitmask_w(v00, r, 3) + bitmask_w(v01, r, 7) +
                     bitmask_w(v10, r, 11) + bitmask_w(v11, r, 15);
      }
    }
  }

#pragma unroll
  for (int j = 0; j < 16; ++j) {
    int pt = base + j * 1024 + (int)threadIdx.x;
    if (pt < n) {
      float4 o;
      o.x = fmaf(2.0f, acc[j][0], -3.0f);
      o.y = fmaf(2.0f, acc[j][1], -3.0f);
      o.z = fmaf(2.0f, acc[j][2], -3.0f);
      o.w = fmaf(2.0f, acc[j][3], -3.0f);
      out4[pt] = o;
    }
  }
}

// ---------------------------------------------------------------------------
// Fallback (ws too small / LDS attr unsupported): gather f32 features
// directly and binarize on the fly.
// ---------------------------------------------------------------------------
__device__ __forceinline__ void plane_accum_f(
    const float4* __restrict__ t, float a, float b,
    float& p0, float& p1, float& p2, float& p3) {
  float sa = a * 512.0f, sb = b * 512.0f;
  float fa = floorf(sa), fb = floorf(sb);
  float wa = sa - fa, wb = sb - fb;
  uint32_t ia = (uint32_t)fa, ib = (uint32_t)fb;
  uint32_t hb0 = ib * PRIME;
  uint32_t hb1 = hb0 + PRIME;
  uint32_t i00 = (ia ^ hb0) & TABLE_MASK;
  uint32_t i01 = (ia ^ hb1) & TABLE_MASK;
  uint32_t i10 = ((ia + 1u) ^ hb0) & TABLE_MASK;
  uint32_t i11 = ((ia + 1u) ^ hb1) & TABLE_MASK;
  float4 f00 = t[i00], f01 = t[i01], f10 = t[i10], f11 = t[i11];
  float omwa = 1.0f - wa, omwb = 1.0f - wb;
  float v00 = omwa * omwb, v01 = omwa * wb, v10 = wa * omwb, v11 = wa * wb;
#define ACCF(F, W)                                                            \
  p0 += ((F).x >= 0.0f) ? (W) : 0.0f;                                         \
  p1 += ((F).y >= 0.0f) ? (W) : 0.0f;                                         \
  p2 += ((F).z >= 0.0f) ? (W) : 0.0f;                                         \
  p3 += ((F).w >= 0.0f) ? (W) : 0.0f;
  ACCF(f00, v00)
  ACCF(f01, v01)
  ACCF(f10, v10)
  ACCF(f11, v11)
#undef ACCF
}

__global__ __launch_bounds__(256) void hash_direct(
    const float* __restrict__ pos, const float4* __restrict__ txy,
    const float4* __restrict__ txz, const float4* __restrict__ tyz,
    float4* __restrict__ out, int n) {
  int i = (int)(blockIdx.x * 256u + threadIdx.x);
  if (i >= n) return;
  float x = pos[3 * i + 0];
  float y = pos[3 * i + 1];
  float z = pos[3 * i + 2];
  float p0 = 0.f, p1 = 0.f, p2 = 0.f, p3 = 0.f;
  plane_accum_f(txy, x, y, p0, p1, p2, p3);
  plane_accum_f(txz, x, z, p0, p1, p2, p3);
  plane_accum_f(tyz, y, z, p0, p1, p2, p3);
  float4 o;
  o.x = fmaf(2.0f, p0, -3.0f);
  o.y = fmaf(2.0f, p1, -3.0f);
  o.z = fmaf(2.0f, p2, -3.0f);
  o.w = fmaf(2.0f, p3, -3.0f);
  out[i] = o;
}

extern "C" void kernel_launch(void* const* d_in, const int* in_sizes, int n_in,
                              void* d_out, int out_size, void* d_ws,
                              size_t ws_size, hipStream_t stream) {
  const float* pos = (const float*)d_in[0];
  const float* txy = (const float*)d_in[1];
  const float* txz = (const float*)d_in[2];
  const float* tyz = (const float*)d_in[3];
  float4* out = (float4*)d_out;
  int n = in_sizes[0] / 3;                       // 4194304
  const size_t corner_ws = (size_t)3 * CORNER_BYTES;   // 395,532 B
  const size_t lds_bytes = (size_t)CORNER_BYTES;       // 131,844 B

  bool lds_ok = ws_size >= corner_ws;
  if (lds_ok) {
    hipError_t e = hipFuncSetAttribute(
        (const void*)hash_planes, hipFuncAttributeMaxDynamicSharedMemorySize,
        (int)lds_bytes);
    if (e != hipSuccess) lds_ok = false;
  }

  if (lds_ok) {
    uint32_t* cornerg = (uint32_t*)d_ws;
    corner3_kernel<<<(3 * CORNER_DWORDS + 255) / 256, 256, 0, stream>>>(
        txy, txz, tyz, cornerg);
    int nblk = (n + PTS_PER_BLOCK - 1) / PTS_PER_BLOCK;
    hash_planes<<<nblk, 1024, lds_bytes, stream>>>(pos, cornerg, out, n);
  } else {
    hash_direct<<<(n + 255) / 256, 256, 0, stream>>>(
        pos, (const float4*)txy, (const float4*)txz, (const float4*)tyz, out,
        n);
  }
}